// Round 8
// baseline (147.909 us; speedup 1.0000x reference)
//
#include <hip/hip_runtime.h>

// Event-warp + bilinear splat, v8.
//   K1 ssort : source-tile counting scatter (no flow read), 512-thr blocks.
//   K2 build2: 2 blocks/source tile, flow tile in LDS, 3x3-ring dest scatter;
//              NEW: wave-ballot ranking (1 LDS atomic per wave per ring tile
//              instead of ~1.1 per record on 9 hot counters).
//   K3 splat : 1x-read ownership-tile splat; (w, w*nts) Q20-packed into ONE
//              ds_add_u64 per corner; paired uint4 record loads; fused spill;
//              pure float4 writeout (no out-memset).
// Inputs (setup_inputs order):
//   d_in[0] flow  : float32 [B,2,H,W]   (ch0 = x-flow, ch1 = y-flow)
//   d_in[1] ts    : float32 [B,N,1]
//   d_in[2] ev_y  : int32   [B,N]
//   d_in[3] ev_x  : int32   [B,N]
//   d_in[4] pol   : int32   [B,N]  (1 = positive, 0 = negative)
// Output: float32 [B,4,H,W] = (iwe_pos, iwe_neg, iwe_pos_ts, iwe_neg_ts)

#define IMG_H 480
#define IMG_W 640

#define OT_H 16
#define OT_W 32
#define OTY (IMG_H / OT_H)        // 30
#define OTX (IMG_W / OT_W)        // 20
#define OT_PER_B (OTY * OTX)      // 600
#define NB 4
#define NT (NB * OT_PER_B)        // 2400

#define ACC_PLANE (OT_H * OT_W)   // 512 cells

// ws layout (byte offsets)
#define SCURS_STRIDE 16                 // u32 stride -> 64 B padded lines
#define WS_SCURS 0                      // NT * 64 B = 153600
#define WS_DCURS 153600                 // NT * 4 B  = 9600
#define WS_SPILLCNT 163200              // 4 B
#define WS_SPILL 163840                 // SPILL_CAP * 16 B = 512 KB
#define SPILL_CAP 32768
#define WS_RECS 688128                  // srecs (NT*cap*8) then drecs (NT*cap*8)

#define SSORT_THREADS 512
#define K1_IPT 2
#define K1_CHUNK (SSORT_THREADS * K1_IPT)   // 1024 events per block

#define Q20 1048576.0f
#define INV_Q20 9.5367431640625e-07f

// ---------------------------------------------------------------------------
__device__ __forceinline__ unsigned mbcnt64(unsigned long long m) {
    // popcount of m restricted to lanes below this lane
    return __builtin_amdgcn_mbcnt_hi((unsigned)(m >> 32),
           __builtin_amdgcn_mbcnt_lo((unsigned)m, 0u));
}

__device__ __forceinline__ void
warp_from(const float* __restrict__ flow, int b, int y, int x, float t,
          float& wy, float& wx, float& nts) {
    const float* fb = flow + (size_t)b * 2 * IMG_H * IMG_W;
    const int pix = y * IMG_W + x;
    const float fx = fb[pix];
    const float fy = fb[IMG_H * IMG_W + pix];
    const float dt = 1.0f - t;
    wy = (float)y + dt * fy;
    wx = (float)x + dt * fx;
    nts = 1.0f - fabsf(1.0f - t);
}

// ---------------------------------------------------------------------------
// K1: counting-scatter by SOURCE tile (key from ev_y/ev_x directly).
__global__ void __launch_bounds__(SSORT_THREADS)
ssort_kernel(const float* __restrict__ flow, const float* __restrict__ ts,
             const int* __restrict__ ev_y, const int* __restrict__ ev_x,
             const int* __restrict__ pol,
             unsigned* __restrict__ scurs, unsigned* __restrict__ spillcnt,
             float4* __restrict__ spill, uint2* __restrict__ srecs,
             int N, int cap) {
    __shared__ unsigned lh[OT_PER_B];
    __shared__ unsigned lbase[OT_PER_B];
    const int tid = threadIdx.x;
    const int b = blockIdx.y;
    const int base = blockIdx.x * K1_CHUNK;

    for (int j = tid; j < OT_PER_B; j += SSORT_THREADS) lh[j] = 0;
    __syncthreads();

    unsigned mK[K1_IPT], ltK[K1_IPT], rkK[K1_IPT];
    float tsK[K1_IPT];

    #pragma unroll
    for (int k = 0; k < K1_IPT; ++k) {
        const int idx = base + k * SSORT_THREADS + tid;
        unsigned lt = 0xFFFFu, rk = 0, m = 0; float t = 0.f;
        if (idx < N) {
            const int i = b * N + idx;
            const int y = ev_y[i];
            const int x = ev_x[i];
            t = ts[i];
            const int p = pol[i];
            lt = (unsigned)((y >> 4) * OTX + (x >> 5));
            rk = atomicAdd(&lh[lt], 1u);
            m = (unsigned)y | ((unsigned)x << 9) | ((unsigned)(p & 1) << 19);
        }
        mK[k] = m; ltK[k] = lt; rkK[k] = rk; tsK[k] = t;
    }
    __syncthreads();

    for (int j = tid; j < OT_PER_B; j += SSORT_THREADS) {
        const unsigned n = lh[j];
        lbase[j] = n ? atomicAdd(&scurs[(size_t)(b * OT_PER_B + j) * SCURS_STRIDE], n)
                     : 0u;
    }
    __syncthreads();

    #pragma unroll
    for (int k = 0; k < K1_IPT; ++k) {
        const unsigned lt = ltK[k];
        if (lt == 0xFFFFu) continue;
        const unsigned slot = lbase[lt] + rkK[k];
        if (slot < (unsigned)cap) {
            uint2 r; r.x = mK[k]; r.y = __float_as_uint(tsK[k]);
            srecs[(size_t)(b * OT_PER_B + lt) * cap + slot] = r;
        } else {
            // rare: process fully now, defer via unrestricted spill
            const int y = (int)(mK[k] & 511u);
            const int x = (int)((mK[k] >> 9) & 1023u);
            const int p = (int)((mK[k] >> 19) & 1u);
            float wy, wx, nts;
            warp_from(flow, b, y, x, tsK[k], wy, wx, nts);
            const unsigned g = atomicAdd(spillcnt, 1u);
            if (g < SPILL_CAP) {
                float4 s; s.x = wy; s.y = wx; s.z = nts;
                s.w = __uint_as_float((unsigned)((b << 1) | p));  // bit31=0
                spill[g] = s;
            }
        }
    }
}

// ---------------------------------------------------------------------------
// K2: 2 blocks per source tile; flow tile (4 KB) in LDS; wave-ballot ranking
// over the 9 ring counters; 8-B quantized dest records.
__global__ void __launch_bounds__(256)
build2_kernel(const float* __restrict__ flow,
              const unsigned* __restrict__ scurs, unsigned* __restrict__ dcurs,
              unsigned* __restrict__ spillcnt, float4* __restrict__ spill,
              const uint2* __restrict__ srecs, uint2* __restrict__ drecs,
              int cap) {
    __shared__ unsigned dh[9];
    __shared__ unsigned dbase[9];
    __shared__ float lflow[2][OT_H][OT_W];   // [ch][ly][lx]
    const int tile = blockIdx.x >> 1;
    const int half = blockIdx.x & 1;
    const int tid  = threadIdx.x;
    const int lane = tid & 63;
    const int b   = tile / OT_PER_B;
    const int lt  = tile % OT_PER_B;
    const int ssy = lt / OTX;
    const int ssx = lt % OTX;

    if (tid < 9) dh[tid] = 0;
    {
        const float* fb = flow + (size_t)b * 2 * IMG_H * IMG_W;
        #pragma unroll
        for (int j = tid; j < 2 * OT_H * OT_W; j += 256) {
            const int ch = j / (OT_H * OT_W);
            const int r  = (j % (OT_H * OT_W)) / OT_W;
            const int c  = j % OT_W;
            lflow[ch][r][c] = fb[(size_t)ch * IMG_H * IMG_W
                                 + (ssy * OT_H + r) * IMG_W + (ssx * OT_W + c)];
        }
    }
    __syncthreads();

    const unsigned cnt = min(scurs[(size_t)tile * SCURS_STRIDE], (unsigned)cap);
    const unsigned hsz = (cnt + 1u) >> 1;
    const unsigned lo  = half * hsz;
    const unsigned hi  = min(cnt, lo + hsz);
    const uint2* sbase = srecs + (size_t)tile * cap;

    float wyK[2], wxK[2], ntsK[2];
    unsigned pK[2], ndK[2], relK[2], rkK[2][4];

    #pragma unroll
    for (int k = 0; k < 2; ++k) {
        unsigned nd = 0, relp = 0, rmask = 0;
        unsigned rels4[4] = {0u, 0u, 0u, 0u};
        float wy = 0.f, wx = 0.f, nts = 0.f; unsigned p = 0;
        const unsigned i = lo + (unsigned)(k * 256 + tid);
        if (i < hi) {
            const uint2 sr = sbase[i];
            const int y = (int)(sr.x & 511u);
            const int x = (int)((sr.x >> 9) & 1023u);
            p = (sr.x >> 19) & 1u;
            const float t = __uint_as_float(sr.y);
            const float fx = lflow[0][y & (OT_H - 1)][x & (OT_W - 1)];
            const float fy = lflow[1][y & (OT_H - 1)][x & (OT_W - 1)];
            const float dt = 1.0f - t;
            wy = (float)y + dt * fy;
            wx = (float)x + dt * fx;
            nts = 1.0f - fabsf(1.0f - t);

            const int iy0 = (int)floorf(wy);
            const int ix0 = (int)floorf(wx);
            int rys[2]; int nry = 0;
            if (iy0 >= 0 && iy0 < IMG_H) rys[nry++] = iy0 >> 4;
            if (iy0 + 1 >= 0 && iy0 + 1 < IMG_H) {
                const int r = (iy0 + 1) >> 4;
                if (nry == 0 || r != rys[0]) rys[nry++] = r;
            }
            int rxs[2]; int nrx = 0;
            if (ix0 >= 0 && ix0 < IMG_W) rxs[nrx++] = ix0 >> 5;
            if (ix0 + 1 >= 0 && ix0 + 1 < IMG_W) {
                const int r = (ix0 + 1) >> 5;
                if (nrx == 0 || r != rxs[0]) rxs[nrx++] = r;
            }
            if (nry > 0 && nrx > 0) {
                for (int a = 0; a < nry; ++a)
                    for (int c = 0; c < nrx; ++c) {
                        const int ry_r = rys[a] - ssy + 1;
                        const int rx_r = rxs[c] - ssx + 1;
                        if ((unsigned)ry_r > 2u || (unsigned)rx_r > 2u) {
                            // outside 3x3 ring: restricted spill for this dest
                            const unsigned g = atomicAdd(spillcnt, 1u);
                            if (g < SPILL_CAP) {
                                float4 s; s.x = wy; s.y = wx; s.z = nts;
                                s.w = __uint_as_float(0x80000000u
                                        | (unsigned)((b << 1) | p)
                                        | ((unsigned)rys[a] << 8)
                                        | ((unsigned)rxs[c] << 16));
                                spill[g] = s;
                            }
                        } else {
                            const unsigned rel = (unsigned)(ry_r * 3 + rx_r);
                            rels4[nd] = rel;
                            relp |= rel << (4 * nd);
                            rmask |= 1u << rel;
                            ++nd;
                        }
                    }
            }
        }

        // -------- wave-ballot ranking (uniform across the wave) --------
        unsigned cnt9[9];
        unsigned myr4[4] = {0u, 0u, 0u, 0u};
        #pragma unroll
        for (int j = 0; j < 9; ++j) {
            const unsigned long long bal = __ballot((rmask >> j) & 1u);
            cnt9[j] = (unsigned)__popcll(bal);
            const unsigned mr = mbcnt64(bal);
            #pragma unroll
            for (int d = 0; d < 4; ++d)
                if (rels4[d] == (unsigned)j) myr4[d] = mr;
        }
        unsigned wbl = 0;
        if (lane < 9 && cnt9[lane]) wbl = atomicAdd(&dh[lane], cnt9[lane]);
        #pragma unroll
        for (int d = 0; d < 4; ++d) {
            const unsigned bj = (unsigned)__shfl((int)wbl, (int)rels4[d]);
            if (d < (int)nd) rkK[k][d] = bj + myr4[d];
        }
        // ---------------------------------------------------------------

        wyK[k] = wy; wxK[k] = wx; ntsK[k] = nts; pK[k] = p;
        ndK[k] = nd; relK[k] = relp;
    }
    __syncthreads();

    if (tid < 9) {
        const unsigned n = dh[tid];
        if (n) {
            const int dty = ssy + tid / 3 - 1;
            const int dtx = ssx + tid % 3 - 1;
            dbase[tid] = atomicAdd(&dcurs[b * OT_PER_B + dty * OTX + dtx], n);
        }
    }
    __syncthreads();

    #pragma unroll
    for (int k = 0; k < 2; ++k) {
        const unsigned nd = ndK[k];
        for (unsigned d = 0; d < nd; ++d) {
            const unsigned rel = (relK[k] >> (4 * d)) & 0xFu;
            const unsigned rr = rkK[k][d];
            const int dty = ssy + (int)(rel / 3) - 1;
            const int dtx = ssx + (int)(rel % 3) - 1;
            const unsigned slot = dbase[rel] + rr;
            if (slot < (unsigned)cap) {
                int qy = __float2int_rn((wyK[k] - 16.0f * dty + 1.0f) * 2048.0f);
                int qx = __float2int_rn((wxK[k] - 32.0f * dtx + 1.0f) * 1024.0f);
                int qt = __float2int_rn(ntsK[k] * 32767.0f);
                qy = min(max(qy, 0), 65535);
                qx = min(max(qx, 0), 65535);
                qt = min(max(qt, 0), 32767);
                uint2 dr;
                dr.x = (unsigned)qy | ((unsigned)qx << 16);
                dr.y = (unsigned)qt | (pK[k] << 15);
                drecs[(size_t)(b * OT_PER_B + dty * OTX + dtx) * cap + slot] = dr;
            } else {
                const unsigned g = atomicAdd(spillcnt, 1u);
                if (g < SPILL_CAP) {
                    float4 s; s.x = wyK[k]; s.y = wxK[k]; s.z = ntsK[k];
                    s.w = __uint_as_float(0x80000000u
                            | (unsigned)((b << 1) | pK[k])
                            | ((unsigned)dty << 8) | ((unsigned)dtx << 16));
                    spill[g] = s;
                }
            }
        }
    }
}

// ---------------------------------------------------------------------------
// K3: one block per ownership tile. Paired uint4 record loads; (w, w*nts)
// Q20-packed ds_add_u64 per corner; fused spill; pure float4 writeout.
__device__ __forceinline__ void
splat_rec(unsigned rx_, unsigned ry_, unsigned long long* __restrict__ acc64) {
    const float ry  = (float)(rx_ & 0xFFFFu) * (1.0f / 2048.0f) - 1.0f;
    const float rx  = (float)(rx_ >> 16)     * (1.0f / 1024.0f) - 1.0f;
    const float nts = (float)(ry_ & 0x7FFFu) * (1.0f / 32767.0f);
    const int p = (int)((ry_ >> 15) & 1u);
    const float byf = floorf(ry), bxf = floorf(rx);
    const int iy0 = (int)byf, ix0 = (int)bxf;
    const float ay = ry - byf, ax = rx - bxf;
    const float wyv[2] = {1.0f - ay, ay};
    const float wxv[2] = {1.0f - ax, ax};
    unsigned long long* accp = acc64 + (p ? 0 : 1) * ACC_PLANE;
    #pragma unroll
    for (int dy = 0; dy < 2; ++dy) {
        const int gy = iy0 + dy;
        if ((unsigned)gy >= (unsigned)OT_H) continue;
        #pragma unroll
        for (int dx = 0; dx < 2; ++dx) {
            const int gx = ix0 + dx;
            if ((unsigned)gx >= (unsigned)OT_W) continue;
            const float w = wyv[dy] * wxv[dx];
            const unsigned qw  = __float2uint_rn(w * Q20);
            const unsigned qwt = __float2uint_rn(w * nts * Q20);
            atomicAdd(&accp[gy * OT_W + gx],
                      ((unsigned long long)qwt << 32) | (unsigned long long)qw);
        }
    }
}

__global__ void __launch_bounds__(256)
splat_kernel(const uint2* __restrict__ drecs, const unsigned* __restrict__ dcurs,
             const float4* __restrict__ spill, const unsigned* __restrict__ spillcnt,
             float* __restrict__ out, int cap) {
    __shared__ unsigned long long acc64[2 * ACC_PLANE];  // [pol(pos,neg)][cell]
    const int tile = blockIdx.x;
    const int tid = threadIdx.x;
    #pragma unroll
    for (int j = tid; j < 2 * ACC_PLANE; j += 256) acc64[j] = 0ull;
    __syncthreads();

    const int myb = tile / OT_PER_B;
    const int rb  = tile % OT_PER_B;
    const int sy  = rb / OTX;
    const int sx  = rb % OTX;

    const unsigned cnt = min(dcurs[tile], (unsigned)cap);
    const uint4* base4 = (const uint4*)(drecs + (size_t)tile * cap);
    const unsigned npair = cnt >> 1;
    for (unsigned u = tid; u < npair; u += 256) {
        const uint4 q = base4[u];          // two records
        splat_rec(q.x, q.y, acc64);
        splat_rec(q.z, q.w, acc64);
    }
    if ((cnt & 1u) && tid == 0) {
        const uint2 r = (drecs + (size_t)tile * cap)[cnt - 1];
        splat_rec(r.x, r.y, acc64);
    }

    // fused spill application (normally zero records)
    const unsigned nsp = min(*spillcnt, (unsigned)SPILL_CAP);
    for (unsigned i = tid; i < nsp; i += 256) {
        const float4 s = spill[i];
        const unsigned meta = __float_as_uint(s.w);
        if ((int)((meta >> 1) & 3u) != myb) continue;
        if (meta & 0x80000000u) {   // restricted to one dest tile
            if ((int)((meta >> 8) & 31u) != sy || (int)((meta >> 16) & 31u) != sx)
                continue;
        }
        const int p = (int)(meta & 1u);
        const float wy = s.x, wx = s.y, nts = s.z;
        const float byf = floorf(wy), bxf = floorf(wx);
        const int iy0 = (int)byf, ix0 = (int)bxf;
        const float ay = wy - byf, ax = wx - bxf;
        const float wyv[2] = {1.0f - ay, ay};
        const float wxv[2] = {1.0f - ax, ax};
        unsigned long long* accp = acc64 + (p ? 0 : 1) * ACC_PLANE;
        #pragma unroll
        for (int dy = 0; dy < 2; ++dy) {
            const int gy = iy0 + dy;
            if ((gy >> 4) != sy) continue;       // ownership (global coords)
            #pragma unroll
            for (int dx = 0; dx < 2; ++dx) {
                const int gx = ix0 + dx;
                if ((gx >> 5) != sx) continue;
                const float w = wyv[dy] * wxv[dx];
                const unsigned qw  = __float2uint_rn(w * Q20);
                const unsigned qwt = __float2uint_rn(w * nts * Q20);
                atomicAdd(&accp[(gy & 15) * OT_W + (gx & 31)],
                          ((unsigned long long)qwt << 32) | (unsigned long long)qw);
            }
        }
    }
    __syncthreads();

    const int y0 = sy * OT_H;
    const int x0 = sx * OT_W;
    float* outb = out + (size_t)myb * 4 * IMG_H * IMG_W;
    {
        const int q = tid;                       // 0..255
        const int pl  = q / (ACC_PLANE / 4);     // 0 = pos, 1 = neg
        const int rem = q % (ACC_PLANE / 4);
        const int ry  = rem / (OT_W / 4);
        const int rx4 = rem % (OT_W / 4);
        float4 c4, t4;
        const unsigned long long* cell = acc64 + pl * ACC_PLANE + rem * 4;
        float* c = &c4.x; float* t = &t4.x;
        #pragma unroll
        for (int j = 0; j < 4; ++j) {
            const unsigned long long v = cell[j];
            c[j] = (float)(unsigned)(v & 0xFFFFFFFFull) * INV_Q20;
            t[j] = (float)(unsigned)(v >> 32) * INV_Q20;
        }
        const size_t off = (size_t)(y0 + ry) * IMG_W + x0 + rx4 * 4;
        *(float4*)(outb + (size_t)pl * IMG_H * IMG_W + off) = c4;
        *(float4*)(outb + (size_t)(pl + 2) * IMG_H * IMG_W + off) = t4;
    }
}

// ---------------------------------------------------------------------------
// Last-resort fallback: direct global atomics (needs zeroed out).
__global__ void __launch_bounds__(256)
event_splat_fallback(const float* __restrict__ flow, const float* __restrict__ ts,
                     const int* __restrict__ ev_y, const int* __restrict__ ev_x,
                     const int* __restrict__ pol, float* __restrict__ out,
                     int N, int total) {
    const int i = blockIdx.x * blockDim.x + threadIdx.x;
    if (i >= total) return;
    const int b = i / N;
    float wy, wx, nts;
    warp_from(flow, b, ev_y[i], ev_x[i], ts[i], wy, wx, nts);
    const int p = pol[i];
    const float byf = floorf(wy), bxf = floorf(wx);
    const int iy0 = (int)byf, ix0 = (int)bxf;
    const float ay = wy - byf, ax = wx - bxf;
    const float wyv[2] = {1.0f - ay, ay};
    const float wxv[2] = {1.0f - ax, ax};
    float* out_c = out + ((size_t)b * 4 + (p ? 0 : 1)) * IMG_H * IMG_W;
    float* out_t = out_c + 2 * IMG_H * IMG_W;
    #pragma unroll
    for (int dy = 0; dy < 2; ++dy) {
        const int gy = iy0 + dy;
        if (gy < 0 || gy >= IMG_H) continue;
        #pragma unroll
        for (int dx = 0; dx < 2; ++dx) {
            const int gx = ix0 + dx;
            if (gx < 0 || gx >= IMG_W) continue;
            const float w = wyv[dy] * wxv[dx];
            const int o = gy * IMG_W + gx;
            atomicAdd(out_c + o, w);
            atomicAdd(out_t + o, w * nts);
        }
    }
}

// ---------------------------------------------------------------------------
extern "C" void kernel_launch(void* const* d_in, const int* in_sizes, int n_in,
                              void* d_out, int out_size, void* d_ws, size_t ws_size,
                              hipStream_t stream) {
    const float* flow = (const float*)d_in[0];
    const float* ts   = (const float*)d_in[1];
    const int*   ev_y = (const int*)d_in[2];
    const int*   ev_x = (const int*)d_in[3];
    const int*   pol  = (const int*)d_in[4];
    float* out = (float*)d_out;

    const int total = in_sizes[2];                  // B*N
    const int B = out_size / (4 * IMG_H * IMG_W);
    const int N = total / B;
    char* ws = (char*)d_ws;

    // cap slots per tile: srec (8 B) + drec (8 B) = 16 B/slot/tile.
    int cap = 0;
    if (ws_size > (size_t)WS_RECS)
        cap = (int)((ws_size - WS_RECS) / ((size_t)NT * 16));
    if (cap > 1024) cap = 1024;
    cap &= ~3;

    if (B == NB && cap >= 640) {
        unsigned* scurs    = (unsigned*)(ws + WS_SCURS);
        unsigned* dcurs    = (unsigned*)(ws + WS_DCURS);
        unsigned* spillcnt = (unsigned*)(ws + WS_SPILLCNT);
        float4*   spill    = (float4*)(ws + WS_SPILL);
        uint2*    srecs    = (uint2*)(ws + WS_RECS);
        uint2*    drecs    = (uint2*)(ws + WS_RECS + (size_t)NT * cap * 8);

        hipMemsetAsync(ws, 0, WS_SPILL, stream);    // scurs + dcurs + spillcnt

        dim3 g1((N + K1_CHUNK - 1) / K1_CHUNK, NB);
        ssort_kernel<<<g1, SSORT_THREADS, 0, stream>>>(flow, ts, ev_y, ev_x, pol,
                                                       scurs, spillcnt, spill,
                                                       srecs, N, cap);
        build2_kernel<<<NT * 2, 256, 0, stream>>>(flow, scurs, dcurs, spillcnt,
                                                  spill, srecs, drecs, cap);
        splat_kernel<<<NT, 256, 0, stream>>>(drecs, dcurs, spill, spillcnt,
                                             out, cap);
        return;
    }

    // last resort
    hipMemsetAsync(d_out, 0, (size_t)out_size * sizeof(float), stream);
    const int blocks = (total + 255) / 256;
    event_splat_fallback<<<blocks, 256, 0, stream>>>(flow, ts, ev_y, ev_x, pol,
                                                     out, N, total);
}

// Round 9
// 145.268 us; speedup vs baseline: 1.0182x; 1.0182x over previous
//
#include <hip/hip_runtime.h>

// Event-warp + bilinear splat, v9.
//   K1 ssort : source-tile counting scatter; PER-WAVE private 600-bin
//              histograms (8x600 LDS) -> no cross-wave same-address RMW
//              chains; one padded global cursor atomic per (block,tile).
//   K2 build2: 2 blocks/source tile, flow tile in LDS, 3x3-ring dest scatter,
//              per-record LDS ranking (round-7 version; ballot reverted).
//   K3 splat : 1x-read ownership-tile splat; (w, w*nts) Q20-packed into ONE
//              ds_add_u64 per corner; paired uint4 loads; fused spill;
//              pure float4 writeout (no out-memset).
// Inputs (setup_inputs order):
//   d_in[0] flow  : float32 [B,2,H,W]   (ch0 = x-flow, ch1 = y-flow)
//   d_in[1] ts    : float32 [B,N,1]
//   d_in[2] ev_y  : int32   [B,N]
//   d_in[3] ev_x  : int32   [B,N]
//   d_in[4] pol   : int32   [B,N]  (1 = positive, 0 = negative)
// Output: float32 [B,4,H,W] = (iwe_pos, iwe_neg, iwe_pos_ts, iwe_neg_ts)

#define IMG_H 480
#define IMG_W 640

#define OT_H 16
#define OT_W 32
#define OTY (IMG_H / OT_H)        // 30
#define OTX (IMG_W / OT_W)        // 20
#define OT_PER_B (OTY * OTX)      // 600
#define NB 4
#define NT (NB * OT_PER_B)        // 2400

#define ACC_PLANE (OT_H * OT_W)   // 512 cells

// ws layout (byte offsets)
#define SCURS_STRIDE 16                 // u32 stride -> 64 B padded lines
#define WS_SCURS 0                      // NT * 64 B = 153600
#define WS_DCURS 153600                 // NT * 4 B  = 9600
#define WS_SPILLCNT 163200              // 4 B
#define WS_SPILL 163840                 // SPILL_CAP * 16 B = 512 KB
#define SPILL_CAP 32768
#define WS_RECS 688128                  // srecs (NT*cap*8) then drecs (NT*cap*8)

#define SSORT_THREADS 512
#define NWAVE (SSORT_THREADS / 64)      // 8
#define K1_IPT 2
#define K1_CHUNK (SSORT_THREADS * K1_IPT)   // 1024 events per block

#define Q20 1048576.0f
#define INV_Q20 9.5367431640625e-07f

// ---------------------------------------------------------------------------
__device__ __forceinline__ void
warp_from(const float* __restrict__ flow, int b, int y, int x, float t,
          float& wy, float& wx, float& nts) {
    const float* fb = flow + (size_t)b * 2 * IMG_H * IMG_W;
    const int pix = y * IMG_W + x;
    const float fx = fb[pix];
    const float fy = fb[IMG_H * IMG_W + pix];
    const float dt = 1.0f - t;
    wy = (float)y + dt * fy;
    wx = (float)x + dt * fx;
    nts = 1.0f - fabsf(1.0f - t);
}

// ---------------------------------------------------------------------------
// K1: counting-scatter by SOURCE tile with per-wave private histograms.
__global__ void __launch_bounds__(SSORT_THREADS)
ssort_kernel(const float* __restrict__ flow, const float* __restrict__ ts,
             const int* __restrict__ ev_y, const int* __restrict__ ev_x,
             const int* __restrict__ pol,
             unsigned* __restrict__ scurs, unsigned* __restrict__ spillcnt,
             float4* __restrict__ spill, uint2* __restrict__ srecs,
             int N, int cap) {
    __shared__ unsigned lh[NWAVE * OT_PER_B];   // [wave][tile] counts -> bases
    const int tid = threadIdx.x;
    const int wave = tid >> 6;
    const int b = blockIdx.y;
    const int base = blockIdx.x * K1_CHUNK;

    for (int j = tid; j < NWAVE * OT_PER_B; j += SSORT_THREADS) lh[j] = 0;
    __syncthreads();

    unsigned mK[K1_IPT], ltK[K1_IPT], rkK[K1_IPT];
    float tsK[K1_IPT];

    // Phase A: wave-private rank
    #pragma unroll
    for (int k = 0; k < K1_IPT; ++k) {
        const int idx = base + k * SSORT_THREADS + tid;
        unsigned lt = 0xFFFFu, rk = 0, m = 0; float t = 0.f;
        if (idx < N) {
            const int i = b * N + idx;
            const int y = ev_y[i];
            const int x = ev_x[i];
            t = ts[i];
            const int p = pol[i];
            lt = (unsigned)((y >> 4) * OTX + (x >> 5));
            rk = atomicAdd(&lh[wave * OT_PER_B + lt], 1u);
            m = (unsigned)y | ((unsigned)x << 9) | ((unsigned)(p & 1) << 19);
        }
        mK[k] = m; ltK[k] = lt; rkK[k] = rk; tsK[k] = t;
    }
    __syncthreads();

    // Phase B: per tile: global reservation + in-place 8-way exclusive scan
    for (int j = tid; j < OT_PER_B; j += SSORT_THREADS) {
        unsigned c[NWAVE]; unsigned tot = 0;
        #pragma unroll
        for (int w = 0; w < NWAVE; ++w) { c[w] = lh[w * OT_PER_B + j]; tot += c[w]; }
        unsigned run = tot
            ? atomicAdd(&scurs[(size_t)(b * OT_PER_B + j) * SCURS_STRIDE], tot)
            : 0u;
        #pragma unroll
        for (int w = 0; w < NWAVE; ++w) { lh[w * OT_PER_B + j] = run; run += c[w]; }
    }
    __syncthreads();

    // Phase C: write records
    #pragma unroll
    for (int k = 0; k < K1_IPT; ++k) {
        const unsigned lt = ltK[k];
        if (lt == 0xFFFFu) continue;
        const unsigned slot = lh[wave * OT_PER_B + lt] + rkK[k];
        if (slot < (unsigned)cap) {
            uint2 r; r.x = mK[k]; r.y = __float_as_uint(tsK[k]);
            srecs[(size_t)(b * OT_PER_B + lt) * cap + slot] = r;
        } else {
            // rare: process fully now, defer via unrestricted spill
            const int y = (int)(mK[k] & 511u);
            const int x = (int)((mK[k] >> 9) & 1023u);
            const int p = (int)((mK[k] >> 19) & 1u);
            float wy, wx, nts;
            warp_from(flow, b, y, x, tsK[k], wy, wx, nts);
            const unsigned g = atomicAdd(spillcnt, 1u);
            if (g < SPILL_CAP) {
                float4 s; s.x = wy; s.y = wx; s.z = nts;
                s.w = __uint_as_float((unsigned)((b << 1) | p));  // bit31=0
                spill[g] = s;
            }
        }
    }
}

// ---------------------------------------------------------------------------
// K2: 2 blocks per source tile; flow tile (4 KB) in LDS; per-record LDS
// ranking on 9 ring counters; 8-B quantized dest records.
__global__ void __launch_bounds__(256)
build2_kernel(const float* __restrict__ flow,
              const unsigned* __restrict__ scurs, unsigned* __restrict__ dcurs,
              unsigned* __restrict__ spillcnt, float4* __restrict__ spill,
              const uint2* __restrict__ srecs, uint2* __restrict__ drecs,
              int cap) {
    __shared__ unsigned dh[9];
    __shared__ unsigned dbase[9];
    __shared__ float lflow[2][OT_H][OT_W];   // [ch][ly][lx]
    const int tile = blockIdx.x >> 1;
    const int half = blockIdx.x & 1;
    const int tid = threadIdx.x;
    const int b   = tile / OT_PER_B;
    const int lt  = tile % OT_PER_B;
    const int ssy = lt / OTX;
    const int ssx = lt % OTX;

    if (tid < 9) dh[tid] = 0;
    {
        const float* fb = flow + (size_t)b * 2 * IMG_H * IMG_W;
        #pragma unroll
        for (int j = tid; j < 2 * OT_H * OT_W; j += 256) {
            const int ch = j / (OT_H * OT_W);
            const int r  = (j % (OT_H * OT_W)) / OT_W;
            const int c  = j % OT_W;
            lflow[ch][r][c] = fb[(size_t)ch * IMG_H * IMG_W
                                 + (ssy * OT_H + r) * IMG_W + (ssx * OT_W + c)];
        }
    }
    __syncthreads();

    const unsigned cnt = min(scurs[(size_t)tile * SCURS_STRIDE], (unsigned)cap);
    const unsigned hsz = (cnt + 1u) >> 1;
    const unsigned lo  = half * hsz;
    const unsigned hi  = min(cnt, lo + hsz);
    const uint2* sbase = srecs + (size_t)tile * cap;

    float wyK[2], wxK[2], ntsK[2];
    unsigned pK[2], ndK[2], relK[2], rk0K[2], rk1K[2], rk2K[2], rk3K[2];

    #pragma unroll
    for (int k = 0; k < 2; ++k) {
        unsigned nd = 0, relp = 0, r0 = 0, r1 = 0, r2 = 0, r3 = 0;
        float wy = 0.f, wx = 0.f, nts = 0.f; unsigned p = 0;
        const unsigned i = lo + (unsigned)(k * 256 + tid);
        if (i < hi) {
            const uint2 sr = sbase[i];
            const int y = (int)(sr.x & 511u);
            const int x = (int)((sr.x >> 9) & 1023u);
            p = (sr.x >> 19) & 1u;
            const float t = __uint_as_float(sr.y);
            const float fx = lflow[0][y & (OT_H - 1)][x & (OT_W - 1)];
            const float fy = lflow[1][y & (OT_H - 1)][x & (OT_W - 1)];
            const float dt = 1.0f - t;
            wy = (float)y + dt * fy;
            wx = (float)x + dt * fx;
            nts = 1.0f - fabsf(1.0f - t);

            const int iy0 = (int)floorf(wy);
            const int ix0 = (int)floorf(wx);
            int rys[2]; int nry = 0;
            if (iy0 >= 0 && iy0 < IMG_H) rys[nry++] = iy0 >> 4;
            if (iy0 + 1 >= 0 && iy0 + 1 < IMG_H) {
                const int r = (iy0 + 1) >> 4;
                if (nry == 0 || r != rys[0]) rys[nry++] = r;
            }
            int rxs[2]; int nrx = 0;
            if (ix0 >= 0 && ix0 < IMG_W) rxs[nrx++] = ix0 >> 5;
            if (ix0 + 1 >= 0 && ix0 + 1 < IMG_W) {
                const int r = (ix0 + 1) >> 5;
                if (nrx == 0 || r != rxs[0]) rxs[nrx++] = r;
            }
            if (nry > 0 && nrx > 0) {
                for (int a = 0; a < nry; ++a)
                    for (int c = 0; c < nrx; ++c) {
                        const int ry_r = rys[a] - ssy + 1;
                        const int rx_r = rxs[c] - ssx + 1;
                        if ((unsigned)ry_r > 2u || (unsigned)rx_r > 2u) {
                            // outside 3x3 ring: restricted spill for this dest
                            const unsigned g = atomicAdd(spillcnt, 1u);
                            if (g < SPILL_CAP) {
                                float4 s; s.x = wy; s.y = wx; s.z = nts;
                                s.w = __uint_as_float(0x80000000u
                                        | (unsigned)((b << 1) | p)
                                        | ((unsigned)rys[a] << 8)
                                        | ((unsigned)rxs[c] << 16));
                                spill[g] = s;
                            }
                        } else {
                            const unsigned rel = (unsigned)(ry_r * 3 + rx_r);
                            relp |= rel << (8 * nd);
                            const unsigned rr = atomicAdd(&dh[rel], 1u);
                            if (nd == 0) r0 = rr; else if (nd == 1) r1 = rr;
                            else if (nd == 2) r2 = rr; else r3 = rr;
                            ++nd;
                        }
                    }
            }
        }
        wyK[k] = wy; wxK[k] = wx; ntsK[k] = nts; pK[k] = p;
        ndK[k] = nd; relK[k] = relp;
        rk0K[k] = r0; rk1K[k] = r1; rk2K[k] = r2; rk3K[k] = r3;
    }
    __syncthreads();

    if (tid < 9) {
        const unsigned n = dh[tid];
        if (n) {
            const int dty = ssy + tid / 3 - 1;
            const int dtx = ssx + tid % 3 - 1;
            dbase[tid] = atomicAdd(&dcurs[b * OT_PER_B + dty * OTX + dtx], n);
        }
    }
    __syncthreads();

    #pragma unroll
    for (int k = 0; k < 2; ++k) {
        const unsigned nd = ndK[k];
        for (unsigned d = 0; d < nd; ++d) {
            const unsigned rel = (relK[k] >> (8 * d)) & 0xFFu;
            const unsigned rr = (d == 0) ? rk0K[k] : (d == 1) ? rk1K[k]
                              : (d == 2) ? rk2K[k] : rk3K[k];
            const int dty = ssy + (int)(rel / 3) - 1;
            const int dtx = ssx + (int)(rel % 3) - 1;
            const unsigned slot = dbase[rel] + rr;
            if (slot < (unsigned)cap) {
                int qy = __float2int_rn((wyK[k] - 16.0f * dty + 1.0f) * 2048.0f);
                int qx = __float2int_rn((wxK[k] - 32.0f * dtx + 1.0f) * 1024.0f);
                int qt = __float2int_rn(ntsK[k] * 32767.0f);
                qy = min(max(qy, 0), 65535);
                qx = min(max(qx, 0), 65535);
                qt = min(max(qt, 0), 32767);
                uint2 dr;
                dr.x = (unsigned)qy | ((unsigned)qx << 16);
                dr.y = (unsigned)qt | (pK[k] << 15);
                drecs[(size_t)(b * OT_PER_B + dty * OTX + dtx) * cap + slot] = dr;
            } else {
                const unsigned g = atomicAdd(spillcnt, 1u);
                if (g < SPILL_CAP) {
                    float4 s; s.x = wyK[k]; s.y = wxK[k]; s.z = ntsK[k];
                    s.w = __uint_as_float(0x80000000u
                            | (unsigned)((b << 1) | pK[k])
                            | ((unsigned)dty << 8) | ((unsigned)dtx << 16));
                    spill[g] = s;
                }
            }
        }
    }
}

// ---------------------------------------------------------------------------
// K3: one block per ownership tile. Paired uint4 record loads; (w, w*nts)
// Q20-packed ds_add_u64 per corner; fused spill; pure float4 writeout.
__device__ __forceinline__ void
splat_rec(unsigned rx_, unsigned ry_, unsigned long long* __restrict__ acc64) {
    const float ry  = (float)(rx_ & 0xFFFFu) * (1.0f / 2048.0f) - 1.0f;
    const float rx  = (float)(rx_ >> 16)     * (1.0f / 1024.0f) - 1.0f;
    const float nts = (float)(ry_ & 0x7FFFu) * (1.0f / 32767.0f);
    const int p = (int)((ry_ >> 15) & 1u);
    const float byf = floorf(ry), bxf = floorf(rx);
    const int iy0 = (int)byf, ix0 = (int)bxf;
    const float ay = ry - byf, ax = rx - bxf;
    const float wyv[2] = {1.0f - ay, ay};
    const float wxv[2] = {1.0f - ax, ax};
    unsigned long long* accp = acc64 + (p ? 0 : 1) * ACC_PLANE;
    #pragma unroll
    for (int dy = 0; dy < 2; ++dy) {
        const int gy = iy0 + dy;
        if ((unsigned)gy >= (unsigned)OT_H) continue;
        #pragma unroll
        for (int dx = 0; dx < 2; ++dx) {
            const int gx = ix0 + dx;
            if ((unsigned)gx >= (unsigned)OT_W) continue;
            const float w = wyv[dy] * wxv[dx];
            const unsigned qw  = __float2uint_rn(w * Q20);
            const unsigned qwt = __float2uint_rn(w * nts * Q20);
            atomicAdd(&accp[gy * OT_W + gx],
                      ((unsigned long long)qwt << 32) | (unsigned long long)qw);
        }
    }
}

__global__ void __launch_bounds__(256)
splat_kernel(const uint2* __restrict__ drecs, const unsigned* __restrict__ dcurs,
             const float4* __restrict__ spill, const unsigned* __restrict__ spillcnt,
             float* __restrict__ out, int cap) {
    __shared__ unsigned long long acc64[2 * ACC_PLANE];  // [pol(pos,neg)][cell]
    const int tile = blockIdx.x;
    const int tid = threadIdx.x;
    #pragma unroll
    for (int j = tid; j < 2 * ACC_PLANE; j += 256) acc64[j] = 0ull;
    __syncthreads();

    const int myb = tile / OT_PER_B;
    const int rb  = tile % OT_PER_B;
    const int sy  = rb / OTX;
    const int sx  = rb % OTX;

    const unsigned cnt = min(dcurs[tile], (unsigned)cap);
    const uint4* base4 = (const uint4*)(drecs + (size_t)tile * cap);
    const unsigned npair = cnt >> 1;
    for (unsigned u = tid; u < npair; u += 256) {
        const uint4 q = base4[u];          // two records
        splat_rec(q.x, q.y, acc64);
        splat_rec(q.z, q.w, acc64);
    }
    if ((cnt & 1u) && tid == 0) {
        const uint2 r = (drecs + (size_t)tile * cap)[cnt - 1];
        splat_rec(r.x, r.y, acc64);
    }

    // fused spill application (normally zero records)
    const unsigned nsp = min(*spillcnt, (unsigned)SPILL_CAP);
    for (unsigned i = tid; i < nsp; i += 256) {
        const float4 s = spill[i];
        const unsigned meta = __float_as_uint(s.w);
        if ((int)((meta >> 1) & 3u) != myb) continue;
        if (meta & 0x80000000u) {   // restricted to one dest tile
            if ((int)((meta >> 8) & 31u) != sy || (int)((meta >> 16) & 31u) != sx)
                continue;
        }
        const int p = (int)(meta & 1u);
        const float wy = s.x, wx = s.y, nts = s.z;
        const float byf = floorf(wy), bxf = floorf(wx);
        const int iy0 = (int)byf, ix0 = (int)bxf;
        const float ay = wy - byf, ax = wx - bxf;
        const float wyv[2] = {1.0f - ay, ay};
        const float wxv[2] = {1.0f - ax, ax};
        unsigned long long* accp = acc64 + (p ? 0 : 1) * ACC_PLANE;
        #pragma unroll
        for (int dy = 0; dy < 2; ++dy) {
            const int gy = iy0 + dy;
            if ((gy >> 4) != sy) continue;       // ownership (global coords)
            #pragma unroll
            for (int dx = 0; dx < 2; ++dx) {
                const int gx = ix0 + dx;
                if ((gx >> 5) != sx) continue;
                const float w = wyv[dy] * wxv[dx];
                const unsigned qw  = __float2uint_rn(w * Q20);
                const unsigned qwt = __float2uint_rn(w * nts * Q20);
                atomicAdd(&accp[(gy & 15) * OT_W + (gx & 31)],
                          ((unsigned long long)qwt << 32) | (unsigned long long)qw);
            }
        }
    }
    __syncthreads();

    const int y0 = sy * OT_H;
    const int x0 = sx * OT_W;
    float* outb = out + (size_t)myb * 4 * IMG_H * IMG_W;
    {
        const int q = tid;                       // 0..255
        const int pl  = q / (ACC_PLANE / 4);     // 0 = pos, 1 = neg
        const int rem = q % (ACC_PLANE / 4);
        const int ry  = rem / (OT_W / 4);
        const int rx4 = rem % (OT_W / 4);
        float4 c4, t4;
        const unsigned long long* cell = acc64 + pl * ACC_PLANE + rem * 4;
        float* c = &c4.x; float* t = &t4.x;
        #pragma unroll
        for (int j = 0; j < 4; ++j) {
            const unsigned long long v = cell[j];
            c[j] = (float)(unsigned)(v & 0xFFFFFFFFull) * INV_Q20;
            t[j] = (float)(unsigned)(v >> 32) * INV_Q20;
        }
        const size_t off = (size_t)(y0 + ry) * IMG_W + x0 + rx4 * 4;
        *(float4*)(outb + (size_t)pl * IMG_H * IMG_W + off) = c4;
        *(float4*)(outb + (size_t)(pl + 2) * IMG_H * IMG_W + off) = t4;
    }
}

// ---------------------------------------------------------------------------
// Last-resort fallback: direct global atomics (needs zeroed out).
__global__ void __launch_bounds__(256)
event_splat_fallback(const float* __restrict__ flow, const float* __restrict__ ts,
                     const int* __restrict__ ev_y, const int* __restrict__ ev_x,
                     const int* __restrict__ pol, float* __restrict__ out,
                     int N, int total) {
    const int i = blockIdx.x * blockDim.x + threadIdx.x;
    if (i >= total) return;
    const int b = i / N;
    float wy, wx, nts;
    warp_from(flow, b, ev_y[i], ev_x[i], ts[i], wy, wx, nts);
    const int p = pol[i];
    const float byf = floorf(wy), bxf = floorf(wx);
    const int iy0 = (int)byf, ix0 = (int)bxf;
    const float ay = wy - byf, ax = wx - bxf;
    const float wyv[2] = {1.0f - ay, ay};
    const float wxv[2] = {1.0f - ax, ax};
    float* out_c = out + ((size_t)b * 4 + (p ? 0 : 1)) * IMG_H * IMG_W;
    float* out_t = out_c + 2 * IMG_H * IMG_W;
    #pragma unroll
    for (int dy = 0; dy < 2; ++dy) {
        const int gy = iy0 + dy;
        if (gy < 0 || gy >= IMG_H) continue;
        #pragma unroll
        for (int dx = 0; dx < 2; ++dx) {
            const int gx = ix0 + dx;
            if (gx < 0 || gx >= IMG_W) continue;
            const float w = wyv[dy] * wxv[dx];
            const int o = gy * IMG_W + gx;
            atomicAdd(out_c + o, w);
            atomicAdd(out_t + o, w * nts);
        }
    }
}

// ---------------------------------------------------------------------------
extern "C" void kernel_launch(void* const* d_in, const int* in_sizes, int n_in,
                              void* d_out, int out_size, void* d_ws, size_t ws_size,
                              hipStream_t stream) {
    const float* flow = (const float*)d_in[0];
    const float* ts   = (const float*)d_in[1];
    const int*   ev_y = (const int*)d_in[2];
    const int*   ev_x = (const int*)d_in[3];
    const int*   pol  = (const int*)d_in[4];
    float* out = (float*)d_out;

    const int total = in_sizes[2];                  // B*N
    const int B = out_size / (4 * IMG_H * IMG_W);
    const int N = total / B;
    char* ws = (char*)d_ws;

    // cap slots per tile: srec (8 B) + drec (8 B) = 16 B/slot/tile.
    int cap = 0;
    if (ws_size > (size_t)WS_RECS)
        cap = (int)((ws_size - WS_RECS) / ((size_t)NT * 16));
    if (cap > 1024) cap = 1024;
    cap &= ~3;

    if (B == NB && cap >= 640) {
        unsigned* scurs    = (unsigned*)(ws + WS_SCURS);
        unsigned* dcurs    = (unsigned*)(ws + WS_DCURS);
        unsigned* spillcnt = (unsigned*)(ws + WS_SPILLCNT);
        float4*   spill    = (float4*)(ws + WS_SPILL);
        uint2*    srecs    = (uint2*)(ws + WS_RECS);
        uint2*    drecs    = (uint2*)(ws + WS_RECS + (size_t)NT * cap * 8);

        hipMemsetAsync(ws, 0, WS_SPILL, stream);    // scurs + dcurs + spillcnt

        dim3 g1((N + K1_CHUNK - 1) / K1_CHUNK, NB);
        ssort_kernel<<<g1, SSORT_THREADS, 0, stream>>>(flow, ts, ev_y, ev_x, pol,
                                                       scurs, spillcnt, spill,
                                                       srecs, N, cap);
        build2_kernel<<<NT * 2, 256, 0, stream>>>(flow, scurs, dcurs, spillcnt,
                                                  spill, srecs, drecs, cap);
        splat_kernel<<<NT, 256, 0, stream>>>(drecs, dcurs, spill, spillcnt,
                                             out, cap);
        return;
    }

    // last resort
    hipMemsetAsync(d_out, 0, (size_t)out_size * sizeof(float), stream);
    const int blocks = (total + 255) / 256;
    event_splat_fallback<<<blocks, 256, 0, stream>>>(flow, ts, ev_y, ev_x, pol,
                                                     out, N, total);
}